// Round 1
// baseline (148.586 us; speedup 1.0000x reference)
//
#include <hip/hip_runtime.h>
#include <hip/hip_fp16.h>

// N=1536 T=20 H=64 E=16 M=128
// pre1[i,j] = Q[j] - P[i]  (Q,P: N x 128 fp16 in d_ws, 768KB)
// out[i]    = max_j relu( relu(Q[j]-P[i]) @ W2 + b2 )
//
// R5: occupancy push. Grid was 2048 single-wave blocks = 2 waves/SIMD; combined
// VGPR+AGPR (~164) allows 3/SIMD. JSPLIT 4->6 => grid 3072 = 12 waves/CU =
// exactly 3/SIMD; launch_bounds(64,3) caps regs at 170 (no new spill pressure).
// b2-add + relu deferred out of the tile loop (max/relu monotone) to trim VALU.

#define NN 1536
#define HH 64
#define EE 16
#define MM 128
#define TT 20
#define NI 3
#define JSPLIT 6
#define NIGRP (NN / NI)      // 512 i-groups
#define NTILE (96 / JSPLIT)  // 16 j-tiles of 16 per wave

typedef _Float16 half8 __attribute__((ext_vector_type(8)));
typedef float f32x4 __attribute__((ext_vector_type(4)));

// grid NN, block 128. Computes Q,P (fp16) and zero-inits out (harness poisons 0xAA).
__global__ __launch_bounds__(128) void precompute_kernel(
    const float* __restrict__ hidden, const float* __restrict__ gt,
    const float* __restrict__ We, const float* __restrict__ be,
    const float* __restrict__ W1, const float* __restrict__ b1,
    _Float16* __restrict__ Q, _Float16* __restrict__ P, float* __restrict__ out)
{
  const int j = blockIdx.x;
  const int m = threadIdx.x;
  const float* hrow = hidden + j * HH;
  // 2 partial sums break the serial fmaf chain (ILP)
  float a0 = 0.f, a1 = 0.f;
  #pragma unroll 8
  for (int h = 0; h < HH; h += 2) {
    a0 = fmaf(hrow[h],     W1[h * MM + m],       a0);
    a1 = fmaf(hrow[h + 1], W1[(h + 1) * MM + m], a1);
  }
  const float a = a0 + a1;
  float ve0 = 0.f, ve1 = 0.f, cm = b1[m];
  #pragma unroll
  for (int e = 0; e < EE; ++e) {
    float w1e = W1[(HH + e) * MM + m];
    ve0 = fmaf(We[e], w1e, ve0);       // We[0][e]
    ve1 = fmaf(We[EE + e], w1e, ve1);  // We[1][e]
    cm  = fmaf(be[e], w1e, cm);
  }
  const float e0 = gt[j * (2 * TT) + 2 * (TT - 1)];
  const float e1 = gt[j * (2 * TT) + 2 * (TT - 1) + 1];
  const float p = fmaf(e0, ve0, e1 * ve1);
  P[j * MM + m] = (_Float16)p;
  Q[j * MM + m] = (_Float16)(a + p + cm);
  if (m < HH) out[j * HH + m] = 0.f;
}

// grid NIGRP*JSPLIT (=3072), block 64 (1 wave). Wave: i0..i0+2, 16 j-tiles.
// __launch_bounds__(64,3): combined VGPR+AGPR cap ~170; estimated live ~164.
__global__ __launch_bounds__(64, 3) void pairmlp_max_kernel(
    const _Float16* __restrict__ Q, const _Float16* __restrict__ P,
    const float* __restrict__ W2, const float* __restrict__ b2,
    float* __restrict__ out)
{
  const int lane = threadIdx.x;
  const int quad = lane >> 4;   // 0..3
  const int lcol = lane & 15;
  const int ig = blockIdx.x % NIGRP;
  const int js = blockIdx.x / NIGRP;
  const int i0 = ig * NI;

  // B fragments: W2 (128x64 fp32) -> fp16, B[k=ks*32+quad*8+jj][n=ct*16+lcol]
  half8 bfrag[4][4];
  float b2v[4];
  #pragma unroll
  for (int ct = 0; ct < 4; ++ct) {
    const int col = ct * 16 + lcol;
    b2v[ct] = b2[col];
    #pragma unroll
    for (int ks = 0; ks < 4; ++ks) {
      half8 b;
      #pragma unroll
      for (int jj = 0; jj < 8; ++jj)
        b[jj] = (_Float16)W2[(ks * 32 + quad * 8 + jj) * HH + col];
      bfrag[ct][ks] = b;
    }
  }

  // P fragments for NI i's: lane's A-frag k-slots (8 halfs per ks), fp16
  half8 pv[NI][4];
  #pragma unroll
  for (int ii = 0; ii < NI; ++ii) {
    const _Float16* prow = P + (i0 + ii) * MM + quad * 8;
    #pragma unroll
    for (int ks = 0; ks < 4; ++ks)
      pv[ii][ks] = *(const half8*)(prow + ks * 32);
  }

  // rmax tracks raw accumulator max; b2 and relu folded in AFTER the loop
  float rmax[NI][4];
  #pragma unroll
  for (int ii = 0; ii < NI; ++ii)
    #pragma unroll
    for (int ct = 0; ct < 4; ++ct) rmax[ii][ct] = -3.0e38f;

  const int jt0 = js * NTILE;
  const _Float16* qbase = Q + lcol * MM + quad * 8;  // + jt*16*MM + ks*32

  // prefetch first tile
  half8 qc[4], qn[4];
  #pragma unroll
  for (int ks = 0; ks < 4; ++ks)
    qc[ks] = *(const half8*)(qbase + (jt0 * 16) * MM + ks * 32);

  const half8 hz = 0;  // splat zero

  for (int t = 0; t < NTILE; ++t) {
    // prefetch next tile (clamped dummy on last iter; data unused)
    const int jl = (t + 1 < NTILE) ? (jt0 + t + 1) : jt0;
    #pragma unroll
    for (int ks = 0; ks < 4; ++ks)
      qn[ks] = *(const half8*)(qbase + (jl * 16) * MM + ks * 32);

    f32x4 acc[NI][4];
    #pragma unroll
    for (int ii = 0; ii < NI; ++ii)
      #pragma unroll
      for (int ct = 0; ct < 4; ++ct) acc[ii][ct] = f32x4{0.f, 0.f, 0.f, 0.f};

    #pragma unroll
    for (int ks = 0; ks < 4; ++ks) {
      #pragma unroll
      for (int ii = 0; ii < NI; ++ii) {
        // A-frag = relu(q - p) as packed fp16 (v_pk_sub_f16 / v_pk_max_f16)
        half8 s = qc[ks] - pv[ii][ks];
        s = __builtin_elementwise_max(s, hz);
        #pragma unroll
        for (int ct = 0; ct < 4; ++ct)
          acc[ii][ct] = __builtin_amdgcn_mfma_f32_16x16x32_f16(s, bfrag[ct][ks], acc[ii][ct], 0, 0, 0);
      }
    }

    // C/D: col=lcol(+ct*16), row(j)=quad*4+reg. Raw max only; +b2/relu deferred.
    #pragma unroll
    for (int ii = 0; ii < NI; ++ii)
      #pragma unroll
      for (int ct = 0; ct < 4; ++ct) {
        const float m01 = fmaxf(acc[ii][ct][0], acc[ii][ct][1]);
        const float m23 = fmaxf(acc[ii][ct][2], acc[ii][ct][3]);
        rmax[ii][ct] = fmaxf(rmax[ii][ct], fmaxf(m01, m23));
      }

    #pragma unroll
    for (int ks = 0; ks < 4; ++ks) qc[ks] = qn[ks];
  }

  // combine the 4 quad-groups (different j rows, same col), then atomic max.
  // v = relu(max_j acc + b2) >= 0, so uint-compare atomicMax is monotone-safe.
  #pragma unroll
  for (int ii = 0; ii < NI; ++ii)
    #pragma unroll
    for (int ct = 0; ct < 4; ++ct) {
      float v = rmax[ii][ct];
      v = fmaxf(v, __shfl_xor(v, 16, 64));
      v = fmaxf(v, __shfl_xor(v, 32, 64));
      v = fmaxf(v + b2v[ct], 0.f);
      if (quad == 0)
        atomicMax((unsigned*)(out + (i0 + ii) * HH + ct * 16 + lcol), __float_as_uint(v));
    }
}

extern "C" void kernel_launch(void* const* d_in, const int* in_sizes, int n_in,
                              void* d_out, int out_size, void* d_ws, size_t ws_size,
                              hipStream_t stream) {
  const float* hidden = (const float*)d_in[0];
  const float* gt     = (const float*)d_in[1];
  const float* We     = (const float*)d_in[2];
  const float* be     = (const float*)d_in[3];
  const float* W1     = (const float*)d_in[4];
  const float* b1     = (const float*)d_in[5];
  const float* W2     = (const float*)d_in[6];
  const float* b2     = (const float*)d_in[7];
  float* out = (float*)d_out;

  _Float16* Qh = (_Float16*)d_ws;     // NN*MM fp16 (384KB)
  _Float16* Ph = Qh + NN * MM;        // NN*MM fp16 (384KB)

  precompute_kernel<<<NN, 128, 0, stream>>>(hidden, gt, We, be, W1, b1, Qh, Ph, out);
  pairmlp_max_kernel<<<NIGRP * JSPLIT, 64, 0, stream>>>(Qh, Ph, W2, b2, out);
}

// Round 2
// 115.725 us; speedup vs baseline: 1.2840x; 1.2840x over previous
//
#include <hip/hip_runtime.h>

// N=1536 T=20 H=64 E=16 M=128
// Qf[j,k] (MFMA-frag-tile layout) , P[j,k]: fp16 in d_ws (384KB each)
// out[i] = max_j relu( relu(Q[j]-P[i]) @ W2 + b2 )
//
// R6: occupancy via footprint cut (R5 lesson: never force waves_per_eu below
// the live set -> 33MB spill traffic). 4-wave blocks share one Q j-tile via
// global_load_lds double-buffer (kills qc/qn prefetch regs, -64); NI=1 per
// wave (pv 48->16, acc 48->16). Est live ~130 < 170 => 3 waves/SIMD natural.
// Q is precomputed directly in fragment-tile layout so staging is linear
// (both-sides-linear, no swizzle needed) and ds_read is lane*16B consecutive.

#define NN 1536
#define HH 64
#define EE 16
#define MM 128
#define TT 20

#define WAVES 4
#define IBLK  WAVES           // 4 i's per block (NI=1 per wave)
#define NIBLK (NN / IBLK)     // 384
#define JSPLIT 2
#define NTILE (96 / JSPLIT)   // 48 j-tiles of 16 per block
#define TILEB 4096            // bytes per Q tile: 16 j x 128 k x 2B

typedef _Float16 half8 __attribute__((ext_vector_type(8)));
typedef float f32x4 __attribute__((ext_vector_type(4)));

__device__ __forceinline__ void gload_lds16(const void* g, void* l) {
  auto gp = (const __attribute__((address_space(1))) unsigned int*)g;
  auto lp = (__attribute__((address_space(3))) unsigned int*)l;
  __builtin_amdgcn_global_load_lds(gp, lp, 16, 0, 0);
}

// grid NN, block 128. Computes Qf (frag-tile layout), P, zero-inits out.
// Qf entry: A[row=j&15][k=m] for tile jt=j>>4 must land where reading lane
// l=(quad<<4)|row finds halfs jj at ((jt*4+ks)*64+l)*8+jj with
// k = ks*32 + (l>>4)*8 + jj  ->  ks=m>>5, l=((m>>3)&3)*16+(j&15), jj=m&7.
__global__ __launch_bounds__(128) void precompute_kernel(
    const float* __restrict__ hidden, const float* __restrict__ gt,
    const float* __restrict__ We, const float* __restrict__ be,
    const float* __restrict__ W1, const float* __restrict__ b1,
    _Float16* __restrict__ Qf, _Float16* __restrict__ P, float* __restrict__ out)
{
  const int j = blockIdx.x;
  const int m = threadIdx.x;
  const float* hrow = hidden + j * HH;
  float a0 = 0.f, a1 = 0.f;
  #pragma unroll 8
  for (int h = 0; h < HH; h += 2) {
    a0 = fmaf(hrow[h],     W1[h * MM + m],       a0);
    a1 = fmaf(hrow[h + 1], W1[(h + 1) * MM + m], a1);
  }
  const float a = a0 + a1;
  float ve0 = 0.f, ve1 = 0.f, cm = b1[m];
  #pragma unroll
  for (int e = 0; e < EE; ++e) {
    float w1e = W1[(HH + e) * MM + m];
    ve0 = fmaf(We[e], w1e, ve0);       // We[0][e]
    ve1 = fmaf(We[EE + e], w1e, ve1);  // We[1][e]
    cm  = fmaf(be[e], w1e, cm);
  }
  const float e0 = gt[j * (2 * TT) + 2 * (TT - 1)];
  const float e1 = gt[j * (2 * TT) + 2 * (TT - 1) + 1];
  const float p = fmaf(e0, ve0, e1 * ve1);
  P[j * MM + m] = (_Float16)p;

  const int jt = j >> 4;
  const int ks = m >> 5;
  const int ln = ((m >> 3) & 3) * 16 + (j & 15);
  const int jj = m & 7;
  Qf[(((jt * 4) + ks) * 64 + ln) * 8 + jj] = (_Float16)(a + p + cm);

  if (m < HH) out[j * HH + m] = 0.f;
}

// grid NIBLK*JSPLIT = 768, block 256 (4 waves). Wave wid owns i = ig*4+wid.
// All 4 waves share the LDS-staged Q j-tile; B-frags + P-frag stay resident.
__global__ __launch_bounds__(256, 3) void pairmlp_max_kernel(
    const _Float16* __restrict__ Qf, const _Float16* __restrict__ P,
    const float* __restrict__ W2, const float* __restrict__ b2,
    float* __restrict__ out)
{
  __shared__ half8 qlds[2 * 256];  // 2 buffers x 4KB

  const int tid  = threadIdx.x;
  const int wid  = tid >> 6;
  const int lane = tid & 63;
  const int quad = lane >> 4;
  const int lcol = lane & 15;
  const int ig = blockIdx.x % NIBLK;
  const int js = blockIdx.x / NIBLK;
  const int i  = ig * IBLK + wid;

  // B fragments: W2 (128x64 fp32) -> fp16, B[k=ks*32+quad*8+jj][n=ct*16+lcol]
  half8 bfrag[4][4];
  #pragma unroll
  for (int ct = 0; ct < 4; ++ct) {
    #pragma unroll
    for (int ks = 0; ks < 4; ++ks) {
      half8 b;
      #pragma unroll
      for (int jj = 0; jj < 8; ++jj)
        b[jj] = (_Float16)W2[(ks * 32 + quad * 8 + jj) * HH + ct * 16 + lcol];
      bfrag[ct][ks] = b;
    }
  }

  // P fragment for this wave's single i
  half8 pv[4];
  #pragma unroll
  for (int ks = 0; ks < 4; ++ks)
    pv[ks] = *(const half8*)(P + i * MM + ks * 32 + quad * 8);

  float rmax[4];
  #pragma unroll
  for (int ct = 0; ct < 4; ++ct) rmax[ct] = -3.0e38f;

  const int jt0 = js * NTILE;
  const char* qsrc = (const char*)Qf + (size_t)jt0 * TILEB + wid * 1024 + lane * 16;
  char* qdst = (char*)qlds + wid * 1024;

  const half8 hz = 0;

  // prologue: stage tile 0 into buf 0
  gload_lds16(qsrc, qdst);
  __syncthreads();

  int buf = 0;
  for (int t = 0; t < NTILE; ++t) {
    // issue next tile's stage into the other buffer (flight hidden under MFMA)
    if (t + 1 < NTILE)
      gload_lds16(qsrc + (size_t)(t + 1) * TILEB, qdst + (buf ^ 1) * TILEB);

    const half8* ql = qlds + buf * 256;
    f32x4 acc[4];

    // ks = 0 seeds the accumulators (no explicit zero-init pass)
    {
      half8 s = ql[lane] - pv[0];
      s = __builtin_elementwise_max(s, hz);
      #pragma unroll
      for (int ct = 0; ct < 4; ++ct)
        acc[ct] = __builtin_amdgcn_mfma_f32_16x16x32_f16(s, bfrag[ct][0], f32x4{0.f, 0.f, 0.f, 0.f}, 0, 0, 0);
    }
    #pragma unroll
    for (int ks = 1; ks < 4; ++ks) {
      half8 s = ql[ks * 64 + lane] - pv[ks];
      s = __builtin_elementwise_max(s, hz);
      #pragma unroll
      for (int ct = 0; ct < 4; ++ct)
        acc[ct] = __builtin_amdgcn_mfma_f32_16x16x32_f16(s, bfrag[ct][ks], acc[ct], 0, 0, 0);
    }

    // C/D: col=lcol+ct*16, row(j)=quad*4+reg. Raw max; +b2/relu deferred.
    #pragma unroll
    for (int ct = 0; ct < 4; ++ct) {
      const float m01 = fmaxf(acc[ct][0], acc[ct][1]);
      const float m23 = fmaxf(acc[ct][2], acc[ct][3]);
      rmax[ct] = fmaxf(rmax[ct], fmaxf(m01, m23));
    }

    // barrier: (a) all waves done reading buf before it is restaged next iter,
    // (b) per-wave vmcnt drain => next iter's reads of buf^1 are safe.
    __syncthreads();
    buf ^= 1;
  }

  // combine quad-groups (different j rows, same col), then atomic max.
  #pragma unroll
  for (int ct = 0; ct < 4; ++ct) {
    float v = rmax[ct];
    v = fmaxf(v, __shfl_xor(v, 16, 64));
    v = fmaxf(v, __shfl_xor(v, 32, 64));
    v = fmaxf(v + b2[ct * 16 + lcol], 0.f);
    if (quad == 0)
      atomicMax((unsigned*)(out + i * HH + ct * 16 + lcol), __float_as_uint(v));
  }
}

extern "C" void kernel_launch(void* const* d_in, const int* in_sizes, int n_in,
                              void* d_out, int out_size, void* d_ws, size_t ws_size,
                              hipStream_t stream) {
  const float* hidden = (const float*)d_in[0];
  const float* gt     = (const float*)d_in[1];
  const float* We     = (const float*)d_in[2];
  const float* be     = (const float*)d_in[3];
  const float* W1     = (const float*)d_in[4];
  const float* b1     = (const float*)d_in[5];
  const float* W2     = (const float*)d_in[6];
  const float* b2     = (const float*)d_in[7];
  float* out = (float*)d_out;

  _Float16* Qf = (_Float16*)d_ws;     // NN*MM fp16 (384KB), frag-tile layout
  _Float16* Ph = Qf + NN * MM;        // NN*MM fp16 (384KB)

  precompute_kernel<<<NN, 128, 0, stream>>>(hidden, gt, We, be, W1, b1, Qf, Ph, out);
  pairmlp_max_kernel<<<NIBLK * JSPLIT, 256, 0, stream>>>(Qf, Ph, W2, b2, out);
}

// Round 3
// 110.841 us; speedup vs baseline: 1.3405x; 1.0441x over previous
//
#include <hip/hip_runtime.h>

// N=1536 T=20 H=64 E=16 M=128
// Qf[j,k] (MFMA-frag-tile layout), P[j,k]: fp16 in d_ws (384KB each)
// out[i] = max_j relu( relu(Q[j]-P[i]) @ W2 + b2 )
//
// R7: fill the idle wave slots. R6 showed VGPR=68 (residency limit ~7
// blocks/CU) but grid only supplied 3 blocks/CU; occupancy 24%, MfmaUtil
// stuck at 27% with ~50% issue slots idle (barrier-lockstep drain).
// (a) JSPLIT 2->4: grid 1536 = 6 blocks/CU -> independent blocks overlap
//     each other's vmcnt/barrier drains.
// (b) 2 tiles per phase: 12 barriers instead of 24, 32 MFMA per drain,
//     2x8KB LDS double-buffer.
// Staging stays both-sides-linear (gload_lds wave-uniform base + lane*16).

#define NN 1536
#define HH 64
#define EE 16
#define MM 128
#define TT 20

#define WAVES 4
#define IBLK  WAVES           // 4 i's per block (1 per wave)
#define NIBLK (NN / IBLK)     // 384
#define JSPLIT 4
#define NTILE (96 / JSPLIT)   // 24 j-tiles of 16 per block
#define TPH 2                 // tiles per phase
#define NPH (NTILE / TPH)     // 12 phases
#define TILEB 4096            // bytes per Q tile: 16 j x 128 k x 2B
#define PHB (TPH * TILEB)     // 8192 bytes per phase buffer

typedef _Float16 half8 __attribute__((ext_vector_type(8)));
typedef float f32x4 __attribute__((ext_vector_type(4)));

__device__ __forceinline__ void gload_lds16(const void* g, void* l) {
  auto gp = (const __attribute__((address_space(1))) unsigned int*)g;
  auto lp = (__attribute__((address_space(3))) unsigned int*)l;
  __builtin_amdgcn_global_load_lds(gp, lp, 16, 0, 0);
}

// grid NN, block 128. Computes Qf (frag-tile layout), P, zero-inits out.
// Qf entry: A[row=j&15][k=m] for tile jt=j>>4 lands where reading lane
// l finds halfs jj at ((jt*4+ks)*64+l)*8+jj with k = ks*32 + (l>>4)*8 + jj
//   ->  ks=m>>5, l=((m>>3)&3)*16+(j&15), jj=m&7.
__global__ __launch_bounds__(128) void precompute_kernel(
    const float* __restrict__ hidden, const float* __restrict__ gt,
    const float* __restrict__ We, const float* __restrict__ be,
    const float* __restrict__ W1, const float* __restrict__ b1,
    _Float16* __restrict__ Qf, _Float16* __restrict__ P, float* __restrict__ out)
{
  const int j = blockIdx.x;
  const int m = threadIdx.x;
  const float* hrow = hidden + j * HH;
  float a0 = 0.f, a1 = 0.f;
  #pragma unroll 8
  for (int h = 0; h < HH; h += 2) {
    a0 = fmaf(hrow[h],     W1[h * MM + m],       a0);
    a1 = fmaf(hrow[h + 1], W1[(h + 1) * MM + m], a1);
  }
  const float a = a0 + a1;
  float ve0 = 0.f, ve1 = 0.f, cm = b1[m];
  #pragma unroll
  for (int e = 0; e < EE; ++e) {
    float w1e = W1[(HH + e) * MM + m];
    ve0 = fmaf(We[e], w1e, ve0);       // We[0][e]
    ve1 = fmaf(We[EE + e], w1e, ve1);  // We[1][e]
    cm  = fmaf(be[e], w1e, cm);
  }
  const float e0 = gt[j * (2 * TT) + 2 * (TT - 1)];
  const float e1 = gt[j * (2 * TT) + 2 * (TT - 1) + 1];
  const float p = fmaf(e0, ve0, e1 * ve1);
  P[j * MM + m] = (_Float16)p;

  const int jt = j >> 4;
  const int ks = m >> 5;
  const int ln = ((m >> 3) & 3) * 16 + (j & 15);
  const int jj = m & 7;
  Qf[(((jt * 4) + ks) * 64 + ln) * 8 + jj] = (_Float16)(a + p + cm);

  if (m < HH) out[j * HH + m] = 0.f;
}

// grid NIBLK*JSPLIT = 1536, block 256 (4 waves). Wave wid owns i = ig*4+wid.
// All 4 waves share the LDS-staged Q phase (2 tiles); B-frags + P-frag resident.
__global__ __launch_bounds__(256, 3) void pairmlp_max_kernel(
    const _Float16* __restrict__ Qf, const _Float16* __restrict__ P,
    const float* __restrict__ W2, const float* __restrict__ b2,
    float* __restrict__ out)
{
  __shared__ half8 qlds[2 * 512];  // 2 phase-buffers x 8KB

  const int tid  = threadIdx.x;
  const int wid  = tid >> 6;
  const int lane = tid & 63;
  const int quad = lane >> 4;
  const int lcol = lane & 15;
  const int ig = blockIdx.x % NIBLK;
  const int js = blockIdx.x / NIBLK;
  const int i  = ig * IBLK + wid;

  // B fragments: W2 (128x64 fp32) -> fp16, B[k=ks*32+quad*8+jj][n=ct*16+lcol]
  half8 bfrag[4][4];
  #pragma unroll
  for (int ct = 0; ct < 4; ++ct) {
    #pragma unroll
    for (int ks = 0; ks < 4; ++ks) {
      half8 b;
      #pragma unroll
      for (int jj = 0; jj < 8; ++jj)
        b[jj] = (_Float16)W2[(ks * 32 + quad * 8 + jj) * HH + ct * 16 + lcol];
      bfrag[ct][ks] = b;
    }
  }

  // P fragment for this wave's single i
  half8 pv[4];
  #pragma unroll
  for (int ks = 0; ks < 4; ++ks)
    pv[ks] = *(const half8*)(P + i * MM + ks * 32 + quad * 8);

  float rmax[4];
  #pragma unroll
  for (int ct = 0; ct < 4; ++ct) rmax[ct] = -3.0e38f;

  const int jt0 = js * NTILE;
  const char* qsrc = (const char*)Qf + (size_t)jt0 * TILEB + wid * 1024 + lane * 16;
  char* qdst = (char*)qlds + wid * 1024;

  const half8 hz = 0;

  // prologue: stage phase 0 (2 tiles) into buffer 0
  gload_lds16(qsrc,         qdst);
  gload_lds16(qsrc + TILEB, qdst + TILEB);
  __syncthreads();

  int buf = 0;
  for (int p = 0; p < NPH; ++p) {
    // issue next phase's stage into the other buffer (hidden under MFMA)
    if (p + 1 < NPH) {
      const char* s = qsrc + (size_t)(p + 1) * PHB;
      char* d = qdst + (buf ^ 1) * PHB;
      gload_lds16(s,         d);
      gload_lds16(s + TILEB, d + TILEB);
    }

    #pragma unroll
    for (int tt = 0; tt < TPH; ++tt) {
      const half8* ql = qlds + buf * 512 + tt * 256;
      f32x4 acc[4];

      // ks = 0 seeds the accumulators
      {
        half8 s = ql[lane] - pv[0];
        s = __builtin_elementwise_max(s, hz);
        #pragma unroll
        for (int ct = 0; ct < 4; ++ct)
          acc[ct] = __builtin_amdgcn_mfma_f32_16x16x32_f16(s, bfrag[ct][0], f32x4{0.f, 0.f, 0.f, 0.f}, 0, 0, 0);
      }
      #pragma unroll
      for (int ks = 1; ks < 4; ++ks) {
        half8 s = ql[ks * 64 + lane] - pv[ks];
        s = __builtin_elementwise_max(s, hz);
        #pragma unroll
        for (int ct = 0; ct < 4; ++ct)
          acc[ct] = __builtin_amdgcn_mfma_f32_16x16x32_f16(s, bfrag[ct][ks], acc[ct], 0, 0, 0);
      }

      // C/D: col=lcol+ct*16, row(j)=quad*4+reg. Raw max; +b2/relu deferred.
      #pragma unroll
      for (int ct = 0; ct < 4; ++ct) {
        const float m01 = fmaxf(acc[ct][0], acc[ct][1]);
        const float m23 = fmaxf(acc[ct][2], acc[ct][3]);
        rmax[ct] = fmaxf(rmax[ct], fmaxf(m01, m23));
      }
    }

    // barrier: all waves done reading buf; per-wave vmcnt drain covers the
    // next phase's reads of buf^1.
    __syncthreads();
    buf ^= 1;
  }

  // combine quad-groups (different j rows, same col), then atomic max.
  #pragma unroll
  for (int ct = 0; ct < 4; ++ct) {
    float v = rmax[ct];
    v = fmaxf(v, __shfl_xor(v, 16, 64));
    v = fmaxf(v, __shfl_xor(v, 32, 64));
    v = fmaxf(v + b2[ct * 16 + lcol], 0.f);
    if (quad == 0)
      atomicMax((unsigned*)(out + i * HH + ct * 16 + lcol), __float_as_uint(v));
  }
}

extern "C" void kernel_launch(void* const* d_in, const int* in_sizes, int n_in,
                              void* d_out, int out_size, void* d_ws, size_t ws_size,
                              hipStream_t stream) {
  const float* hidden = (const float*)d_in[0];
  const float* gt     = (const float*)d_in[1];
  const float* We     = (const float*)d_in[2];
  const float* be     = (const float*)d_in[3];
  const float* W1     = (const float*)d_in[4];
  const float* b1     = (const float*)d_in[5];
  const float* W2     = (const float*)d_in[6];
  const float* b2     = (const float*)d_in[7];
  float* out = (float*)d_out;

  _Float16* Qf = (_Float16*)d_ws;     // NN*MM fp16 (384KB), frag-tile layout
  _Float16* Ph = Qf + NN * MM;        // NN*MM fp16 (384KB)

  precompute_kernel<<<NN, 128, 0, stream>>>(hidden, gt, We, be, W1, b1, Qf, Ph, out);
  pairmlp_max_kernel<<<NIBLK * JSPLIT, 256, 0, stream>>>(Qf, Ph, W2, b2, out);
}